// Round 4
// baseline (710.528 us; speedup 1.0000x reference)
//
#include <hip/hip_runtime.h>
#include <math.h>

#define NN 20000
#define NE 320000
#define NB 128
#define SLOPE 0.2f
#define BN_EPS 1e-5f

__device__ __forceinline__ unsigned int enc_f(float f) {
    unsigned int b = __float_as_uint(f);
    return (b & 0x80000000u) ? ~b : (b | 0x80000000u);
}
__device__ __forceinline__ float dec_f(unsigned int u) {
    unsigned int b = (u & 0x80000000u) ? (u & 0x7FFFFFFFu) : ~u;
    return __uint_as_float(b);
}
__device__ __forceinline__ unsigned short f2bf(float f) {
    unsigned int u = __float_as_uint(f);
    unsigned int r = (u + 0x7FFFu + ((u >> 16) & 1u)) >> 16;
    return (unsigned short)r;
}
__device__ __forceinline__ float bf2f(unsigned short h) {
    return __uint_as_float(((unsigned int)h) << 16);
}

// ---------- CSR build ----------
__global__ __launch_bounds__(256) void k_hist(const int* __restrict__ dst, int* __restrict__ deg) {
    int e = blockIdx.x * 256 + threadIdx.x;
    if (e < NE) atomicAdd(&deg[dst[e]], 1);
}

__global__ __launch_bounds__(256) void k_scan(const int* __restrict__ deg, int* __restrict__ rowptr,
                                              int* __restrict__ cursor) {
    __shared__ int ssum[256];
    __shared__ int soff[256];
    const int CH = 79; // 256*79 = 20224 >= NN
    int t = threadIdx.x;
    int base = t * CH;
    int s = 0;
    for (int i = 0; i < CH; ++i) { int idx = base + i; if (idx < NN) s += deg[idx]; }
    ssum[t] = s;
    __syncthreads();
    if (t == 0) {
        int run = 0;
        for (int i = 0; i < 256; ++i) { soff[i] = run; run += ssum[i]; }
        rowptr[NN] = run;
    }
    __syncthreads();
    int run = soff[t];
    for (int i = 0; i < CH; ++i) {
        int idx = base + i;
        if (idx < NN) { rowptr[idx] = run; cursor[idx] = run; run += deg[idx]; }
    }
}

// perm[e] = CSR slot; csr_sb[slot] = src | (batch[src] << 20); csr_d[slot] = dst
__global__ __launch_bounds__(256) void k_scatter(const int* __restrict__ src, const int* __restrict__ dst,
                                                 const int* __restrict__ batch,
                                                 int* __restrict__ cursor, int* __restrict__ perm,
                                                 int* __restrict__ csr_sb, int* __restrict__ csr_d) {
    int e = blockIdx.x * 256 + threadIdx.x;
    if (e >= NE) return;
    int d = dst[e];
    int pos = atomicAdd(&cursor[d], 1);
    perm[e] = pos;
    int s = src[e];
    csr_sb[pos] = s | (batch[s] << 20);
    csr_d[pos] = d;
}

// ---------- per-layer precompute ----------
__global__ __launch_bounds__(256) void k_p1(const float* __restrict__ We, const float* __restrict__ atte,
                                            float* __restrict__ ve01, float* __restrict__ w2e01) {
    int L = blockIdx.x;
    const float* WeL = We + (size_t)L * 128 * 128;
    const float* aeL = atte + L * 128;
    int t = threadIdx.x;
    int h = (t >> 6) & 1;
    int k = t & 63;
    int row = (t < 128) ? k : (64 + k);
    float acc = 0.f;
    for (int c = 0; c < 64; ++c) acc += WeL[row * 128 + h * 64 + c] * aeL[h * 64 + c];
    if (t < 128) ve01[L * 128 + t] = acc;
    else        w2e01[L * 128 + (t - 128)] = acc;
}

__global__ __launch_bounds__(256) void k_p2(const float* __restrict__ ins, const float* __restrict__ Wl,
                                            const float* __restrict__ w2e,
                                            float* __restrict__ insl, float* __restrict__ ce) {
    int t = threadIdx.x;
    if (blockIdx.x < 64) {
        int idx = blockIdx.x * 256 + t;
        int b = idx >> 7, j = idx & 127;
        float acc = 0.f;
        for (int k = 0; k < 64; ++k) acc += ins[b * 64 + k] * Wl[(64 + k) * 128 + j];
        insl[idx] = acc;
    } else {
        int b = t >> 1, h = t & 1;
        float acc = 0.f;
        for (int k = 0; k < 64; ++k) acc += ins[b * 64 + k] * w2e[h * 64 + k];
        ce[t] = acc;
    }
}

// ---------- edge dot for BOTH layers, written in CSR order ----------
__global__ __launch_bounds__(256) void k_edot(const float* __restrict__ eattr, const int* __restrict__ perm,
                                              const float* __restrict__ ve01, float4* __restrict__ ae4) {
    __shared__ float sv[256];
    int t = threadIdx.x;
    sv[t] = ve01[t];
    __syncthreads();
    int e = blockIdx.x * 256 + t;
    if (e >= NE) return;
    const float4* row = (const float4*)(eattr + (size_t)e * 64);
    float a00 = 0.f, a01 = 0.f, a10 = 0.f, a11 = 0.f;
#pragma unroll
    for (int q = 0; q < 16; ++q) {
        float4 f = row[q];
        int k = q * 4;
        a00 += f.x * sv[k] + f.y * sv[k + 1] + f.z * sv[k + 2] + f.w * sv[k + 3];
        a01 += f.x * sv[64 + k] + f.y * sv[64 + k + 1] + f.z * sv[64 + k + 2] + f.w * sv[64 + k + 3];
        a10 += f.x * sv[128 + k] + f.y * sv[128 + k + 1] + f.z * sv[128 + k + 2] + f.w * sv[128 + k + 3];
        a11 += f.x * sv[192 + k] + f.y * sv[192 + k + 1] + f.z * sv[192 + k + 2] + f.w * sv[192 + k + 3];
    }
    ae4[perm[e]] = make_float4(a00, a01, a10, a11);
}

// ---------- node linear + attention coefficients (xl stored bf16) ----------
__global__ __launch_bounds__(256) void k_node(const float* __restrict__ hcur, const float* __restrict__ Wl,
                                              const float* __restrict__ insl, const int* __restrict__ batch,
                                              const float* __restrict__ attl, const float* __restrict__ attr_,
                                              unsigned short* __restrict__ xlh, float* __restrict__ al, float* __restrict__ ar) {
    __shared__ float sh[8 * 64];
    int t = threadIdx.x;
    int row0 = blockIdx.x * 8;
    for (int idx = t; idx < 512; idx += 256) {
        int r = idx >> 6, k = idx & 63;
        int n = row0 + r;
        sh[idx] = (n < NN) ? hcur[n * 64 + k] : 0.f;
    }
    __syncthreads();
    int w = t >> 6, lane = t & 63;
    int h = w & 1;
    int rbase = (w >> 1) * 4;
    int j = h * 64 + lane;
    float attlv = attl[j];
    float attrv = attr_[j];
    float acc0 = 0.f, acc1 = 0.f, acc2 = 0.f, acc3 = 0.f;
    for (int k = 0; k < 64; ++k) {
        float wv = Wl[k * 128 + j];
        acc0 += sh[(rbase + 0) * 64 + k] * wv;
        acc1 += sh[(rbase + 1) * 64 + k] * wv;
        acc2 += sh[(rbase + 2) * 64 + k] * wv;
        acc3 += sh[(rbase + 3) * 64 + k] * wv;
    }
    float accs[4] = {acc0, acc1, acc2, acc3};
    for (int rr = 0; rr < 4; ++rr) {
        int n = row0 + rbase + rr;
        if (n >= NN) break;
        int b = batch[n];
        float v = accs[rr] + insl[b * 128 + j];
        xlh[(size_t)n * 128 + j] = f2bf(v);
        float pl = v * attlv, pr = v * attrv;
        for (int off = 32; off > 0; off >>= 1) {
            pl += __shfl_xor(pl, off);
            pr += __shfl_xor(pr, off);
        }
        if (lane == 0) { al[n * 2 + h] = pl; ar[n * 2 + h] = pr; }
    }
}

// ---------- attention logits in CSR order + segment max ----------
__global__ __launch_bounds__(256) void k_attn(const int* __restrict__ csr_sb, const int* __restrict__ csr_d,
                                              const float4* __restrict__ ae4, int layer,
                                              const float2* __restrict__ al2, const float2* __restrict__ ar2,
                                              const float2* __restrict__ ce2,
                                              float2* __restrict__ a2, unsigned int* __restrict__ m_enc) {
    int p = blockIdx.x * 256 + threadIdx.x;
    if (p >= NE) return;
    int sb = csr_sb[p];
    int s = sb & 0xFFFFF, b = sb >> 20;
    int d = csr_d[p];
    float4 ae = ae4[p];
    float2 als = al2[s];
    float2 ard = ar2[d];
    float2 cb = ce2[b];
    float a0 = als.x + ard.x + (layer ? ae.z : ae.x) + cb.x;
    float a1 = als.y + ard.y + (layer ? ae.w : ae.y) + cb.y;
    a0 = (a0 > 0.f) ? a0 : SLOPE * a0;
    a1 = (a1 > 0.f) ? a1 : SLOPE * a1;
    a2[p] = make_float2(a0, a1);
    atomicMax(&m_enc[d * 2 + 0], enc_f(a0));
    atomicMax(&m_enc[d * 2 + 1], enc_f(a1));
}

// ---------- edge-parallel segmented SpMM ----------
// Block stages 256 CSR slots; two 128-thread groups each walk every other edge
// with a register accumulator per channel, flushing on dst change.
__global__ __launch_bounds__(256) void k_spmm(const int* __restrict__ csr_sb, const int* __restrict__ csr_d,
                                              const float2* __restrict__ a2, const unsigned int* __restrict__ m_enc,
                                              const unsigned short* __restrict__ xlh,
                                              float* __restrict__ out_acc, float* __restrict__ ssum) {
    __shared__ int   s_src[256];
    __shared__ int   s_dst[256];
    __shared__ float s_ex0[256];
    __shared__ float s_ex1[256];
    int t = threadIdx.x;
    int base = blockIdx.x * 256;
    int p = base + t;
    if (p < NE) {
        int d = csr_d[p];
        float2 a = a2[p];
        float m0 = dec_f(m_enc[d * 2 + 0]);
        float m1 = dec_f(m_enc[d * 2 + 1]);
        s_src[t] = csr_sb[p] & 0xFFFFF;
        s_dst[t] = d;
        s_ex0[t] = __expf(a.x - m0);
        s_ex1[t] = __expf(a.y - m1);
    } else {
        s_src[t] = 0; s_dst[t] = -1; s_ex0[t] = 0.f; s_ex1[t] = 0.f;
    }
    __syncthreads();
    int c = t & 127;
    int g = t >> 7;
    int h = c >> 6;
    int cnt = min(256, NE - base);
    bool lead = ((c & 63) == 0);
    float acc = 0.f, ssacc = 0.f;
    int cur_d = s_dst[g];
    for (int j = g; j < cnt; j += 2) {
        int d = s_dst[j];
        if (d != cur_d) {
            atomicAdd(&out_acc[(size_t)cur_d * 128 + c], acc);
            if (lead) atomicAdd(&ssum[cur_d * 2 + h], ssacc);
            acc = 0.f; ssacc = 0.f; cur_d = d;
        }
        int s = s_src[j];
        float ex = h ? s_ex1[j] : s_ex0[j];
        float xv = bf2f(xlh[(size_t)s * 128 + c]);
        acc += ex * xv;
        if (lead) ssacc += ex;
    }
    if (cur_d >= 0) {
        atomicAdd(&out_acc[(size_t)cur_d * 128 + c], acc);
        if (lead) atomicAdd(&ssum[cur_d * 2 + h], ssacc);
    }
}

// ---------- finalize layer0: normalize + mean heads + bias + residual + BN stats ----------
__global__ __launch_bounds__(256) void k_fin0(const float* __restrict__ out_acc, const float* __restrict__ ssum,
                                              const float* __restrict__ bias, const float* __restrict__ hprev,
                                              float* __restrict__ hnew, float* __restrict__ bnsum, float* __restrict__ bnsumsq) {
    __shared__ float sa[256], sb_[256];
    int t = threadIdx.x;
    int r = t >> 6, c = t & 63;
    int n = blockIdx.x * 4 + r;
    float v = 0.f;
    if (n < NN) {
        float s0 = ssum[n * 2 + 0] + 1e-16f;
        float s1 = ssum[n * 2 + 1] + 1e-16f;
        v = 0.5f * (out_acc[(size_t)n * 128 + c] / s0 + out_acc[(size_t)n * 128 + 64 + c] / s1)
            + bias[c] + hprev[(size_t)n * 64 + c];
        hnew[(size_t)n * 64 + c] = v;
    }
    sa[t] = v; sb_[t] = v * v;
    __syncthreads();
    if (t < 64) {
        float a = sa[t] + sa[t + 64] + sa[t + 128] + sa[t + 192];
        float b = sb_[t] + sb_[t + 64] + sb_[t + 128] + sb_[t + 192];
        atomicAdd(&bnsum[t], a);
        atomicAdd(&bnsumsq[t], b);
    }
}

__global__ __launch_bounds__(256) void k_bn(float* __restrict__ hbuf, const float* __restrict__ bnsum,
                                            const float* __restrict__ bnsumsq,
                                            const float* __restrict__ gamma, const float* __restrict__ beta) {
    int idx = blockIdx.x * 256 + threadIdx.x;
    if (idx >= NN * 64) return;
    int c = idx & 63;
    float mu = bnsum[c] * (1.f / NN);
    float var = bnsumsq[c] * (1.f / NN) - mu * mu;
    float v = (hbuf[idx] - mu) * rsqrtf(var + BN_EPS) * gamma[c] + beta[c];
    hbuf[idx] = (v > 0.f) ? v : 0.f;
}

__global__ __launch_bounds__(256) void k_fin1(const float* __restrict__ out_acc, const float* __restrict__ ssum,
                                              const float* __restrict__ bias, const float* __restrict__ hprev,
                                              float* __restrict__ out) {
    int idx = blockIdx.x * 256 + threadIdx.x;
    if (idx >= NN * 64) return;
    int n = idx >> 6, c = idx & 63;
    float s0 = ssum[n * 2 + 0] + 1e-16f;
    float s1 = ssum[n * 2 + 1] + 1e-16f;
    out[idx] = 0.5f * (out_acc[(size_t)n * 128 + c] / s0 + out_acc[(size_t)n * 128 + 64 + c] / s1)
               + bias[c] + hprev[idx];
}

extern "C" void kernel_launch(void* const* d_in, const int* in_sizes, int n_in,
                              void* d_out, int out_size, void* d_ws, size_t ws_size,
                              hipStream_t stream) {
    (void)in_sizes; (void)n_in; (void)out_size; (void)ws_size;
    const float* x     = (const float*)d_in[0];
    const int*   eidx  = (const int*)d_in[1];
    const float* eattr = (const float*)d_in[2];
    const float* instr = (const float*)d_in[3];
    const int*   batch = (const int*)d_in[4];
    const float* W_l   = (const float*)d_in[5];
    const float* W_e   = (const float*)d_in[6];
    const float* att_l = (const float*)d_in[7];
    const float* att_r = (const float*)d_in[8];
    const float* att_e = (const float*)d_in[9];
    const float* bias  = (const float*)d_in[10];
    const float* bn_g  = (const float*)d_in[11];
    const float* bn_b  = (const float*)d_in[12];
    float* out = (float*)d_out;

    const int* src = eidx;
    const int* dst = eidx + NE;

    char* ws = (char*)d_ws;
    int*    deg     = (int*)ws;        ws += NN * 4;
    int*    rowptr  = (int*)ws;        ws += (NN + 1) * 4;
    int*    cursor  = (int*)ws;        ws += NN * 4 + 4; // pad to 8B align
    int*    perm    = (int*)ws;        ws += (size_t)NE * 4;
    int*    csr_sb  = (int*)ws;        ws += (size_t)NE * 4;
    int*    csr_d   = (int*)ws;        ws += (size_t)NE * 4;
    float4* ae4     = (float4*)ws;     ws += (size_t)NE * 16;
    float2* a2      = (float2*)ws;     ws += (size_t)NE * 8;
    unsigned short* xlh = (unsigned short*)ws; ws += (size_t)NN * 128 * 2;
    float*  al      = (float*)ws;      ws += NN * 2 * 4;
    float*  ar      = (float*)ws;      ws += NN * 2 * 4;
    float*  ssum    = (float*)ws;      ws += NN * 2 * 4;
    unsigned int* m_enc = (unsigned int*)ws; ws += NN * 2 * 4;
    float*  out_acc = (float*)ws;      ws += (size_t)NN * 128 * 4;
    float*  insl    = (float*)ws;      ws += 128 * 128 * 4;
    float*  ve01    = (float*)ws;      ws += 256 * 4;
    float*  w2e01   = (float*)ws;      ws += 256 * 4;
    float*  ce      = (float*)ws;      ws += 256 * 4;
    float*  hbuf    = (float*)ws;      ws += (size_t)NN * 64 * 4;
    float*  bnsum   = (float*)ws;      ws += 64 * 4;
    float*  bnsumsq = (float*)ws;      ws += 64 * 4;

    hipMemsetAsync(deg, 0, NN * 4, stream);
    hipMemsetAsync(bnsum, 0, 128 * 4, stream); // bnsum + bnsumsq
    k_hist<<<(NE + 255) / 256, 256, 0, stream>>>(dst, deg);
    k_scan<<<1, 256, 0, stream>>>(deg, rowptr, cursor);
    k_scatter<<<(NE + 255) / 256, 256, 0, stream>>>(src, dst, batch, cursor, perm, csr_sb, csr_d);

    k_p1<<<2, 256, 0, stream>>>(W_e, att_e, ve01, w2e01);
    k_edot<<<(NE + 255) / 256, 256, 0, stream>>>(eattr, perm, ve01, ae4);

    for (int i = 0; i < 2; ++i) {
        const float* hcur  = (i == 0) ? x : hbuf;
        const float* hprev = hcur;
        float* hnew = (i == 0) ? hbuf : out;
        const float* Wl_i  = W_l + (size_t)i * 128 * 128;
        const float* ins_i = instr + (size_t)i * NB * 64;

        hipMemsetAsync(m_enc, 0, NN * 2 * 4, stream);
        hipMemsetAsync(ssum, 0, NN * 2 * 4, stream);
        hipMemsetAsync(out_acc, 0, (size_t)NN * 128 * 4, stream);

        k_p2<<<65, 256, 0, stream>>>(ins_i, Wl_i, w2e01 + i * 128, insl, ce);
        k_node<<<(NN + 7) / 8, 256, 0, stream>>>(hcur, Wl_i, insl, batch,
                                                 att_l + i * 128, att_r + i * 128, xlh, al, ar);
        k_attn<<<(NE + 255) / 256, 256, 0, stream>>>(csr_sb, csr_d, ae4, i,
                                                     (const float2*)al, (const float2*)ar,
                                                     (const float2*)ce, a2, m_enc);
        k_spmm<<<(NE + 255) / 256, 256, 0, stream>>>(csr_sb, csr_d, a2, m_enc, xlh, out_acc, ssum);
        if (i == 0) {
            k_fin0<<<(NN + 3) / 4, 256, 0, stream>>>(out_acc, ssum, bias, x, hbuf, bnsum, bnsumsq);
            k_bn<<<(NN * 64 + 255) / 256, 256, 0, stream>>>(hbuf, bnsum, bnsumsq, bn_g, bn_b);
        } else {
            k_fin1<<<(NN * 64 + 255) / 256, 256, 0, stream>>>(out_acc, ssum, bias + 64, hbuf, out);
        }
    }
}

// Round 5
// 542.949 us; speedup vs baseline: 1.3086x; 1.3086x over previous
//
#include <hip/hip_runtime.h>
#include <math.h>

#define NN 20000
#define NE 320000
#define NB 128
#define SLOPE 0.2f
#define BN_EPS 1e-5f

__device__ __forceinline__ unsigned int enc_f(float f) {
    unsigned int b = __float_as_uint(f);
    return (b & 0x80000000u) ? ~b : (b | 0x80000000u);
}
__device__ __forceinline__ float dec_f(unsigned int u) {
    unsigned int b = (u & 0x80000000u) ? (u & 0x7FFFFFFFu) : ~u;
    return __uint_as_float(b);
}
__device__ __forceinline__ unsigned short f2bf(float f) {
    unsigned int u = __float_as_uint(f);
    unsigned int r = (u + 0x7FFFu + ((u >> 16) & 1u)) >> 16;
    return (unsigned short)r;
}
__device__ __forceinline__ float bf2f(unsigned short h) {
    return __uint_as_float(((unsigned int)h) << 16);
}

// ---------- CSR build ----------
__global__ __launch_bounds__(256) void k_hist(const int* __restrict__ dst, int* __restrict__ deg) {
    int e = blockIdx.x * 256 + threadIdx.x;
    if (e < NE) atomicAdd(&deg[dst[e]], 1);
}

__global__ __launch_bounds__(256) void k_scan(const int* __restrict__ deg, int* __restrict__ rowptr,
                                              int* __restrict__ cursor) {
    __shared__ int ssum[256];
    __shared__ int soff[256];
    const int CH = 79;
    int t = threadIdx.x;
    int base = t * CH;
    int s = 0;
    for (int i = 0; i < CH; ++i) { int idx = base + i; if (idx < NN) s += deg[idx]; }
    ssum[t] = s;
    __syncthreads();
    if (t == 0) {
        int run = 0;
        for (int i = 0; i < 256; ++i) { soff[i] = run; run += ssum[i]; }
        rowptr[NN] = run;
    }
    __syncthreads();
    int run = soff[t];
    for (int i = 0; i < CH; ++i) {
        int idx = base + i;
        if (idx < NN) { rowptr[idx] = run; cursor[idx] = run; run += deg[idx]; }
    }
}

__global__ __launch_bounds__(256) void k_scatter(const int* __restrict__ src, const int* __restrict__ dst,
                                                 const int* __restrict__ batch,
                                                 int* __restrict__ cursor, int* __restrict__ perm,
                                                 int* __restrict__ csr_sb, int* __restrict__ csr_d) {
    int e = blockIdx.x * 256 + threadIdx.x;
    if (e >= NE) return;
    int d = dst[e];
    int pos = atomicAdd(&cursor[d], 1);
    perm[e] = pos;
    int s = src[e];
    csr_sb[pos] = s | (batch[s] << 20);
    csr_d[pos] = d;
}

// ---------- per-layer precompute ----------
__global__ __launch_bounds__(256) void k_p1(const float* __restrict__ We, const float* __restrict__ atte,
                                            float* __restrict__ ve01, float* __restrict__ w2e01) {
    int L = blockIdx.x;
    const float* WeL = We + (size_t)L * 128 * 128;
    const float* aeL = atte + L * 128;
    int t = threadIdx.x;
    int h = (t >> 6) & 1;
    int k = t & 63;
    int row = (t < 128) ? k : (64 + k);
    float acc = 0.f;
    for (int c = 0; c < 64; ++c) acc += WeL[row * 128 + h * 64 + c] * aeL[h * 64 + c];
    if (t < 128) ve01[L * 128 + t] = acc;
    else        w2e01[L * 128 + (t - 128)] = acc;
}

__global__ __launch_bounds__(256) void k_p2(const float* __restrict__ ins, const float* __restrict__ Wl,
                                            const float* __restrict__ w2e,
                                            float* __restrict__ insl, float* __restrict__ ce) {
    int t = threadIdx.x;
    if (blockIdx.x < 64) {
        int idx = blockIdx.x * 256 + t;
        int b = idx >> 7, j = idx & 127;
        float acc = 0.f;
        for (int k = 0; k < 64; ++k) acc += ins[b * 64 + k] * Wl[(64 + k) * 128 + j];
        insl[idx] = acc;
    } else {
        int b = t >> 1, h = t & 1;
        float acc = 0.f;
        for (int k = 0; k < 64; ++k) acc += ins[b * 64 + k] * w2e[h * 64 + k];
        ce[t] = acc;
    }
}

// ---------- edge dot for BOTH layers, CSR order ----------
__global__ __launch_bounds__(256) void k_edot(const float* __restrict__ eattr, const int* __restrict__ perm,
                                              const float* __restrict__ ve01, float4* __restrict__ ae4) {
    __shared__ float sv[256];
    int t = threadIdx.x;
    sv[t] = ve01[t];
    __syncthreads();
    int e = blockIdx.x * 256 + t;
    if (e >= NE) return;
    const float4* row = (const float4*)(eattr + (size_t)e * 64);
    float a00 = 0.f, a01 = 0.f, a10 = 0.f, a11 = 0.f;
#pragma unroll
    for (int q = 0; q < 16; ++q) {
        float4 f = row[q];
        int k = q * 4;
        a00 += f.x * sv[k] + f.y * sv[k + 1] + f.z * sv[k + 2] + f.w * sv[k + 3];
        a01 += f.x * sv[64 + k] + f.y * sv[64 + k + 1] + f.z * sv[64 + k + 2] + f.w * sv[64 + k + 3];
        a10 += f.x * sv[128 + k] + f.y * sv[128 + k + 1] + f.z * sv[128 + k + 2] + f.w * sv[128 + k + 3];
        a11 += f.x * sv[192 + k] + f.y * sv[192 + k + 1] + f.z * sv[192 + k + 2] + f.w * sv[192 + k + 3];
    }
    ae4[perm[e]] = make_float4(a00, a01, a10, a11);
}

// ---------- node linear + attention coefficients (xl stored bf16) ----------
__global__ __launch_bounds__(256) void k_node(const float* __restrict__ hcur, const float* __restrict__ Wl,
                                              const float* __restrict__ insl, const int* __restrict__ batch,
                                              const float* __restrict__ attl, const float* __restrict__ attr_,
                                              unsigned short* __restrict__ xlh, float* __restrict__ al, float* __restrict__ ar) {
    __shared__ float sh[8 * 64];
    int t = threadIdx.x;
    int row0 = blockIdx.x * 8;
    for (int idx = t; idx < 512; idx += 256) {
        int r = idx >> 6, k = idx & 63;
        int n = row0 + r;
        sh[idx] = (n < NN) ? hcur[n * 64 + k] : 0.f;
    }
    __syncthreads();
    int w = t >> 6, lane = t & 63;
    int h = w & 1;
    int rbase = (w >> 1) * 4;
    int j = h * 64 + lane;
    float attlv = attl[j];
    float attrv = attr_[j];
    float acc0 = 0.f, acc1 = 0.f, acc2 = 0.f, acc3 = 0.f;
    for (int k = 0; k < 64; ++k) {
        float wv = Wl[k * 128 + j];
        acc0 += sh[(rbase + 0) * 64 + k] * wv;
        acc1 += sh[(rbase + 1) * 64 + k] * wv;
        acc2 += sh[(rbase + 2) * 64 + k] * wv;
        acc3 += sh[(rbase + 3) * 64 + k] * wv;
    }
    float accs[4] = {acc0, acc1, acc2, acc3};
    for (int rr = 0; rr < 4; ++rr) {
        int n = row0 + rbase + rr;
        if (n >= NN) break;
        int b = batch[n];
        float v = accs[rr] + insl[b * 128 + j];
        xlh[(size_t)n * 128 + j] = f2bf(v);
        float pl = v * attlv, pr = v * attrv;
        for (int off = 32; off > 0; off >>= 1) {
            pl += __shfl_xor(pl, off);
            pr += __shfl_xor(pr, off);
        }
        if (lane == 0) { al[n * 2 + h] = pl; ar[n * 2 + h] = pr; }
    }
}

// ---------- attention logits in CSR order + segment max ----------
__global__ __launch_bounds__(256) void k_attn(const int* __restrict__ csr_sb, const int* __restrict__ csr_d,
                                              const float4* __restrict__ ae4, int layer,
                                              const float2* __restrict__ al2, const float2* __restrict__ ar2,
                                              const float2* __restrict__ ce2,
                                              float2* __restrict__ a2, unsigned int* __restrict__ m_enc) {
    int p = blockIdx.x * 256 + threadIdx.x;
    if (p >= NE) return;
    int sb = csr_sb[p];
    int s = sb & 0xFFFFF, b = sb >> 20;
    int d = csr_d[p];
    float4 ae = ae4[p];
    float2 als = al2[s];
    float2 ard = ar2[d];
    float2 cb = ce2[b];
    float a0 = als.x + ard.x + (layer ? ae.z : ae.x) + cb.x;
    float a1 = als.y + ard.y + (layer ? ae.w : ae.y) + cb.y;
    a0 = (a0 > 0.f) ? a0 : SLOPE * a0;
    a1 = (a1 > 0.f) ? a1 : SLOPE * a1;
    a2[p] = make_float2(a0, a1);
    atomicMax(&m_enc[d * 2 + 0], enc_f(a0));
    atomicMax(&m_enc[d * 2 + 1], enc_f(a1));
}

// ---------- ex = exp(a - m), packed edge record, segment sum ----------
__global__ __launch_bounds__(256) void k_exp(const int* __restrict__ csr_sb, const int* __restrict__ csr_d,
                                             const float2* __restrict__ a2, const unsigned int* __restrict__ m_enc,
                                             int4* __restrict__ rec, float* __restrict__ ssum) {
    int p = blockIdx.x * 256 + threadIdx.x;
    if (p >= NE) return;
    int d = csr_d[p];
    float2 a = a2[p];
    float ex0 = __expf(a.x - dec_f(m_enc[d * 2 + 0]));
    float ex1 = __expf(a.y - dec_f(m_enc[d * 2 + 1]));
    int s = csr_sb[p] & 0xFFFFF;
    rec[p] = make_int4(s, __float_as_int(ex0), __float_as_int(ex1), 0);
    atomicAdd(&ssum[d * 2 + 0], ex0);
    atomicAdd(&ssum[d * 2 + 1], ex1);
}

// ---------- gather: 1 wave/node, lane = channel pair; pure independent loads ----------
__global__ __launch_bounds__(256) void k_gather(const int* __restrict__ rowptr, const int4* __restrict__ rec,
                                                const unsigned int* __restrict__ xl32, const float2* __restrict__ ssum2,
                                                const float* __restrict__ bias, const float* __restrict__ hprev,
                                                float* __restrict__ hnew) {
    int t = threadIdx.x;
    int w = t >> 6, lane = t & 63;
    int n = blockIdx.x * 4 + w;
    if (n >= NN) return;
    int r0 = rowptr[n], r1 = rowptr[n + 1];
    float acc0 = 0.f, acc1 = 0.f;
    const unsigned int* xlp = xl32 + lane;
#pragma unroll 4
    for (int p = r0; p < r1; ++p) {
        int4 r = rec[p];                       // 16B broadcast load (wave-uniform addr)
        float ex = (lane < 32) ? __int_as_float(r.y) : __int_as_float(r.z);
        unsigned int pr = xlp[(size_t)r.x * 64]; // 2 bf16 channels, coalesced 256B/wave
        acc0 += ex * bf2f((unsigned short)(pr & 0xFFFFu));
        acc1 += ex * bf2f((unsigned short)(pr >> 16));
    }
    float2 ss = ssum2[n];
    float inv = 1.f / (((lane < 32) ? ss.x : ss.y) + 1e-16f);
    acc0 *= inv; acc1 *= inv;
    float o0 = 0.5f * (acc0 + __shfl_xor(acc0, 32));
    float o1 = 0.5f * (acc1 + __shfl_xor(acc1, 32));
    if (lane < 32) {
        float2 hv = ((const float2*)(hprev + (size_t)n * 64))[lane];
        float2 bv = ((const float2*)bias)[lane];
        float2 o;
        o.x = o0 + bv.x + hv.x;
        o.y = o1 + bv.y + hv.y;
        ((float2*)(hnew + (size_t)n * 64))[lane] = o;
    }
}

// ---------- BN stats: per-block partials (no hot atomics) ----------
__global__ __launch_bounds__(256) void k_bnstat(const float* __restrict__ hbuf,
                                                float* __restrict__ part, float* __restrict__ partsq) {
    __shared__ float sA[256], sB[256];
    int t = threadIdx.x;
    int c = t & 63, r = t >> 6;
    int n0 = blockIdx.x * 80;
    float s = 0.f, s2 = 0.f;
    for (int i = 0; i < 20; ++i) {
        float v = hbuf[(size_t)(n0 + i * 4 + r) * 64 + c];
        s += v; s2 += v * v;
    }
    sA[t] = s; sB[t] = s2;
    __syncthreads();
    if (t < 64) {
        part[blockIdx.x * 64 + t]   = sA[t] + sA[t + 64] + sA[t + 128] + sA[t + 192];
        partsq[blockIdx.x * 64 + t] = sB[t] + sB[t + 64] + sB[t + 128] + sB[t + 192];
    }
}

__global__ __launch_bounds__(256) void k_bnred(const float* __restrict__ part, const float* __restrict__ partsq,
                                               const float* __restrict__ gamma, const float* __restrict__ beta,
                                               float* __restrict__ scsh) {
    __shared__ float sA[256], sB[256];
    int t = threadIdx.x;
    int c = t & 63, q = t >> 6;
    float s = 0.f, s2 = 0.f;
    for (int j = q; j < 250; j += 4) { s += part[j * 64 + c]; s2 += partsq[j * 64 + c]; }
    sA[t] = s; sB[t] = s2;
    __syncthreads();
    if (t < 64) {
        float su = sA[t] + sA[t + 64] + sA[t + 128] + sA[t + 192];
        float sq = sB[t] + sB[t + 64] + sB[t + 128] + sB[t + 192];
        float mu = su * (1.f / NN);
        float var = sq * (1.f / NN) - mu * mu;
        float sc = gamma[t] * rsqrtf(var + BN_EPS);
        scsh[t] = sc;
        scsh[64 + t] = beta[t] - mu * sc;
    }
}

__global__ __launch_bounds__(256) void k_bn(float* __restrict__ hbuf, const float* __restrict__ scsh) {
    int idx = blockIdx.x * 256 + threadIdx.x;
    if (idx >= NN * 64) return;
    int c = idx & 63;
    float v = hbuf[idx] * scsh[c] + scsh[64 + c];
    hbuf[idx] = (v > 0.f) ? v : 0.f;
}

extern "C" void kernel_launch(void* const* d_in, const int* in_sizes, int n_in,
                              void* d_out, int out_size, void* d_ws, size_t ws_size,
                              hipStream_t stream) {
    (void)in_sizes; (void)n_in; (void)out_size; (void)ws_size;
    const float* x     = (const float*)d_in[0];
    const int*   eidx  = (const int*)d_in[1];
    const float* eattr = (const float*)d_in[2];
    const float* instr = (const float*)d_in[3];
    const int*   batch = (const int*)d_in[4];
    const float* W_l   = (const float*)d_in[5];
    const float* W_e   = (const float*)d_in[6];
    const float* att_l = (const float*)d_in[7];
    const float* att_r = (const float*)d_in[8];
    const float* att_e = (const float*)d_in[9];
    const float* bias  = (const float*)d_in[10];
    const float* bn_g  = (const float*)d_in[11];
    const float* bn_b  = (const float*)d_in[12];
    float* out = (float*)d_out;

    const int* src = eidx;
    const int* dst = eidx + NE;

    char* ws = (char*)d_ws;
    float4* ae4     = (float4*)ws;     ws += (size_t)NE * 16;
    int4*   rec     = (int4*)ws;       ws += (size_t)NE * 16;
    float2* a2      = (float2*)ws;     ws += (size_t)NE * 8;
    unsigned short* xlh = (unsigned short*)ws; ws += (size_t)NN * 128 * 2;
    int*    perm    = (int*)ws;        ws += (size_t)NE * 4;
    int*    csr_sb  = (int*)ws;        ws += (size_t)NE * 4;
    int*    csr_d   = (int*)ws;        ws += (size_t)NE * 4;
    int*    deg     = (int*)ws;        ws += NN * 4;
    int*    rowptr  = (int*)ws;        ws += (NN + 1) * 4 + 4;
    int*    cursor  = (int*)ws;        ws += NN * 4;
    float*  al      = (float*)ws;      ws += NN * 2 * 4;
    float*  ar      = (float*)ws;      ws += NN * 2 * 4;
    float*  ssum    = (float*)ws;      ws += NN * 2 * 4;
    unsigned int* m_enc = (unsigned int*)ws; ws += NN * 2 * 4;
    float*  insl    = (float*)ws;      ws += 128 * 128 * 4;
    float*  ve01    = (float*)ws;      ws += 256 * 4;
    float*  w2e01   = (float*)ws;      ws += 256 * 4;
    float*  ce      = (float*)ws;      ws += 256 * 4;
    float*  hbuf    = (float*)ws;      ws += (size_t)NN * 64 * 4;
    float*  part    = (float*)ws;      ws += 250 * 64 * 4;
    float*  partsq  = (float*)ws;      ws += 250 * 64 * 4;
    float*  scsh    = (float*)ws;      ws += 128 * 4;

    hipMemsetAsync(deg, 0, NN * 4, stream);
    k_hist<<<(NE + 255) / 256, 256, 0, stream>>>(dst, deg);
    k_scan<<<1, 256, 0, stream>>>(deg, rowptr, cursor);
    k_scatter<<<(NE + 255) / 256, 256, 0, stream>>>(src, dst, batch, cursor, perm, csr_sb, csr_d);

    k_p1<<<2, 256, 0, stream>>>(W_e, att_e, ve01, w2e01);
    k_edot<<<(NE + 255) / 256, 256, 0, stream>>>(eattr, perm, ve01, ae4);

    for (int i = 0; i < 2; ++i) {
        const float* hcur  = (i == 0) ? x : hbuf;
        float* hnew = (i == 0) ? hbuf : out;
        const float* Wl_i  = W_l + (size_t)i * 128 * 128;
        const float* ins_i = instr + (size_t)i * NB * 64;

        hipMemsetAsync(m_enc, 0, NN * 2 * 4, stream);
        hipMemsetAsync(ssum, 0, NN * 2 * 4, stream);

        k_p2<<<65, 256, 0, stream>>>(ins_i, Wl_i, w2e01 + i * 128, insl, ce);
        k_node<<<(NN + 7) / 8, 256, 0, stream>>>(hcur, Wl_i, insl, batch,
                                                 att_l + i * 128, att_r + i * 128, xlh, al, ar);
        k_attn<<<(NE + 255) / 256, 256, 0, stream>>>(csr_sb, csr_d, ae4, i,
                                                     (const float2*)al, (const float2*)ar,
                                                     (const float2*)ce, a2, m_enc);
        k_exp<<<(NE + 255) / 256, 256, 0, stream>>>(csr_sb, csr_d, a2, m_enc, rec, ssum);
        k_gather<<<NN / 4, 256, 0, stream>>>(rowptr, rec, (const unsigned int*)xlh,
                                             (const float2*)ssum, bias + i * 64, hcur, hnew);
        if (i == 0) {
            k_bnstat<<<250, 256, 0, stream>>>(hbuf, part, partsq);
            k_bnred<<<1, 256, 0, stream>>>(part, partsq, bn_g, bn_b, scsh);
            k_bn<<<(NN * 64 + 255) / 256, 256, 0, stream>>>(hbuf, scsh);
        }
    }
}

// Round 6
// 306.495 us; speedup vs baseline: 2.3182x; 1.7715x over previous
//
#include <hip/hip_runtime.h>
#include <math.h>

#define NN 20000
#define NE 320000
#define NB 128
#define SLOPE 0.2f
#define BN_EPS 1e-5f
#define NBLK 79   // ceil(NN/256)

__device__ __forceinline__ unsigned short f2bf(float f) {
    unsigned int u = __float_as_uint(f);
    unsigned int r = (u + 0x7FFFu + ((u >> 16) & 1u)) >> 16;
    return (unsigned short)r;
}
__device__ __forceinline__ float bf2f(unsigned short h) {
    return __uint_as_float(((unsigned int)h) << 16);
}

// ---------- CSR build ----------
__global__ __launch_bounds__(256) void k_hist(const int* __restrict__ dst, int* __restrict__ deg) {
    int e = blockIdx.x * 256 + threadIdx.x;
    if (e < NE) atomicAdd(&deg[dst[e]], 1);
}

// stage A: per-block sums of deg
__global__ __launch_bounds__(256) void k_scanA(const int* __restrict__ deg, int* __restrict__ bsum) {
    __shared__ int wsum[4];
    int t = threadIdx.x;
    int idx = blockIdx.x * 256 + t;
    int v = (idx < NN) ? deg[idx] : 0;
    for (int off = 32; off > 0; off >>= 1) v += __shfl_xor(v, off);
    if ((t & 63) == 0) wsum[t >> 6] = v;
    __syncthreads();
    if (t == 0) bsum[blockIdx.x] = wsum[0] + wsum[1] + wsum[2] + wsum[3];
}

// stage B: 1 wave scans the 79 block sums (Hillis-Steele in-register)
__global__ __launch_bounds__(64) void k_scanB(const int* __restrict__ bsum, int* __restrict__ boff,
                                              int* __restrict__ rowptr) {
    int l = threadIdx.x;
    int v0 = (l < NBLK) ? bsum[l] : 0;
    int v1 = (64 + l < NBLK) ? bsum[64 + l] : 0;
    int o0 = v0, o1 = v1;
    for (int off = 1; off < 64; off <<= 1) { int u = __shfl_up(v0, off); if (l >= off) v0 += u; }
    int tot0 = __shfl(v0, 63);
    for (int off = 1; off < 64; off <<= 1) { int u = __shfl_up(v1, off); if (l >= off) v1 += u; }
    int tot1 = __shfl(v1, 63);
    if (l < NBLK) boff[l] = v0 - o0;
    if (64 + l < NBLK) boff[64 + l] = tot0 + v1 - o1;
    if (l == 0) rowptr[NN] = tot0 + tot1;
}

// stage C: block-local exclusive scan + block offset -> rowptr, cursor
__global__ __launch_bounds__(256) void k_scanC(const int* __restrict__ deg, const int* __restrict__ boff,
                                               int* __restrict__ rowptr, int* __restrict__ cursor) {
    __shared__ int wsum[4];
    int t = threadIdx.x, lane = t & 63, w = t >> 6;
    int idx = blockIdx.x * 256 + t;
    int v = (idx < NN) ? deg[idx] : 0;
    int incl = v;
    for (int off = 1; off < 64; off <<= 1) { int u = __shfl_up(incl, off); if (lane >= off) incl += u; }
    if (lane == 63) wsum[w] = incl;
    __syncthreads();
    int pre = 0;
    for (int i = 0; i < w; ++i) pre += wsum[i];
    int excl = incl - v + pre + boff[blockIdx.x];
    if (idx < NN) { rowptr[idx] = excl; cursor[idx] = excl; }
}

// ---------- precompute: ve (edge-dot vectors) + w2e, both layers ----------
__global__ __launch_bounds__(256) void k_p1(const float* __restrict__ We, const float* __restrict__ atte,
                                            float* __restrict__ ve01, float* __restrict__ w2e01) {
    int L = blockIdx.x;
    const float* WeL = We + (size_t)L * 128 * 128;
    const float* aeL = atte + L * 128;
    int t = threadIdx.x;
    int h = (t >> 6) & 1;
    int k = t & 63;
    int row = (t < 128) ? k : (64 + k);
    float acc = 0.f;
    for (int c = 0; c < 64; ++c) acc += WeL[row * 128 + h * 64 + c] * aeL[h * 64 + c];
    if (t < 128) ve01[L * 128 + t] = acc;
    else        w2e01[L * 128 + (t - 128)] = acc;
}

// ---------- insl + ce for BOTH layers in one dispatch ----------
__global__ __launch_bounds__(256) void k_p2both(const float* __restrict__ instr, const float* __restrict__ Wl,
                                                const float* __restrict__ w2e01,
                                                float* __restrict__ insl01, float* __restrict__ ce01) {
    int blk = blockIdx.x, t = threadIdx.x;
    if (blk < 128) {
        int L = blk >> 6;
        int idx = (blk & 63) * 256 + t;
        int b = idx >> 7, j = idx & 127;
        const float* ins = instr + (size_t)L * NB * 64;
        const float* WlL = Wl + (size_t)L * 128 * 128;
        float acc = 0.f;
        for (int k = 0; k < 64; ++k) acc += ins[b * 64 + k] * WlL[(64 + k) * 128 + j];
        insl01[(size_t)L * 16384 + idx] = acc;
    } else {
        int L = blk - 128;
        int b = t >> 1, h = t & 1;
        const float* ins = instr + (size_t)L * NB * 64;
        const float* w2 = w2e01 + L * 128 + h * 64;
        float acc = 0.f;
        for (int k = 0; k < 64; ++k) acc += ins[b * 64 + k] * w2[k];
        ce01[L * 256 + b * 2 + h] = acc;
    }
}

// ---------- fused scatter + edge dot (both layers), written at CSR slot ----------
__global__ __launch_bounds__(256) void k_sced(const int* __restrict__ src, const int* __restrict__ dst,
                                              const float* __restrict__ eattr, const float* __restrict__ ve01,
                                              int* __restrict__ cursor,
                                              int* __restrict__ csr_s, int* __restrict__ csr_d,
                                              float4* __restrict__ ae4) {
    __shared__ float sv[256];
    int t = threadIdx.x;
    sv[t] = ve01[t];
    __syncthreads();
    int e = blockIdx.x * 256 + t;
    if (e >= NE) return;
    int s = src[e], d = dst[e];
    const float4* row = (const float4*)(eattr + (size_t)e * 64);
    float a00 = 0.f, a01 = 0.f, a10 = 0.f, a11 = 0.f;
#pragma unroll
    for (int q = 0; q < 16; ++q) {
        float4 f = row[q];
        int k = q * 4;
        a00 += f.x * sv[k] + f.y * sv[k + 1] + f.z * sv[k + 2] + f.w * sv[k + 3];
        a01 += f.x * sv[64 + k] + f.y * sv[64 + k + 1] + f.z * sv[64 + k + 2] + f.w * sv[64 + k + 3];
        a10 += f.x * sv[128 + k] + f.y * sv[128 + k + 1] + f.z * sv[128 + k + 2] + f.w * sv[128 + k + 3];
        a11 += f.x * sv[192 + k] + f.y * sv[192 + k + 1] + f.z * sv[192 + k + 2] + f.w * sv[192 + k + 3];
    }
    int pos = atomicAdd(&cursor[d], 1);
    csr_s[pos] = s;
    csr_d[pos] = d;
    ae4[pos] = make_float4(a00, a01, a10, a11);
}

// ---------- node linear: xl (bf16) + alc (= al + ce[batch]) + ar; optional fused BN+relu on input ----------
__global__ __launch_bounds__(256) void k_node(const float* __restrict__ hcur, const float* __restrict__ Wl,
                                              const float* __restrict__ insl, const int* __restrict__ batch,
                                              const float* __restrict__ attl, const float* __restrict__ attr_,
                                              const float2* __restrict__ ce2,
                                              const float* __restrict__ scsh, int use_bn,
                                              unsigned short* __restrict__ xlh,
                                              float* __restrict__ alc, float* __restrict__ ar) {
    __shared__ float sh[8 * 64];
    int t = threadIdx.x;
    int row0 = blockIdx.x * 8;
    for (int idx = t; idx < 512; idx += 256) {
        int r = idx >> 6, k = idx & 63;
        int n = row0 + r;
        float hv = (n < NN) ? hcur[n * 64 + k] : 0.f;
        if (use_bn) hv = fmaxf(hv * scsh[k] + scsh[64 + k], 0.f);
        sh[idx] = hv;
    }
    __syncthreads();
    int w = t >> 6, lane = t & 63;
    int h = w & 1;
    int rbase = (w >> 1) * 4;
    int j = h * 64 + lane;
    float attlv = attl[j];
    float attrv = attr_[j];
    float acc0 = 0.f, acc1 = 0.f, acc2 = 0.f, acc3 = 0.f;
    for (int k = 0; k < 64; ++k) {
        float wv = Wl[k * 128 + j];
        acc0 += sh[(rbase + 0) * 64 + k] * wv;
        acc1 += sh[(rbase + 1) * 64 + k] * wv;
        acc2 += sh[(rbase + 2) * 64 + k] * wv;
        acc3 += sh[(rbase + 3) * 64 + k] * wv;
    }
    float accs[4] = {acc0, acc1, acc2, acc3};
    for (int rr = 0; rr < 4; ++rr) {
        int n = row0 + rbase + rr;
        if (n >= NN) break;
        int b = batch[n];
        float v = accs[rr] + insl[b * 128 + j];
        xlh[(size_t)n * 128 + j] = f2bf(v);
        float pl = v * attlv, pr = v * attrv;
        for (int off = 32; off > 0; off >>= 1) {
            pl += __shfl_xor(pl, off);
            pr += __shfl_xor(pr, off);
        }
        if (lane == 0) {
            float2 cb = ce2[b];
            alc[n * 2 + h] = pl + (h ? cb.y : cb.x);
            ar[n * 2 + h] = pr;
        }
    }
}

// ---------- fused logits + exp (no max subtraction; shift-invariant softmax) ----------
__global__ __launch_bounds__(256) void k_attnexp(const int* __restrict__ csr_s, const int* __restrict__ csr_d,
                                                 const float4* __restrict__ ae4, int layer,
                                                 const float2* __restrict__ alc2, const float2* __restrict__ ar2,
                                                 int4* __restrict__ rec) {
    int p = blockIdx.x * 256 + threadIdx.x;
    if (p >= NE) return;
    int s = csr_s[p], d = csr_d[p];
    float4 ae = ae4[p];
    float2 a_l = alc2[s];
    float2 a_r = ar2[d];
    float a0 = a_l.x + a_r.x + (layer ? ae.z : ae.x);
    float a1 = a_l.y + a_r.y + (layer ? ae.w : ae.y);
    a0 = (a0 > 0.f) ? a0 : SLOPE * a0;
    a1 = (a1 > 0.f) ? a1 : SLOPE * a1;
    rec[p] = make_int4(s, __float_as_int(__expf(a0)), __float_as_int(__expf(a1)), 0);
}

// ---------- gather: 1 wave/node; ssum accumulated in-wave; optional BN on residual ----------
__global__ __launch_bounds__(256) void k_gather(const int* __restrict__ rowptr, const int4* __restrict__ rec,
                                                const unsigned int* __restrict__ xl32,
                                                const float* __restrict__ bias, const float* __restrict__ hprev,
                                                const float* __restrict__ scsh, int use_bn,
                                                float* __restrict__ hnew) {
    int t = threadIdx.x;
    int w = t >> 6, lane = t & 63;
    int n = blockIdx.x * 4 + w;
    if (n >= NN) return;
    int r0 = rowptr[n], r1 = rowptr[n + 1];
    float acc0 = 0.f, acc1 = 0.f, ss = 0.f;
    const unsigned int* xlp = xl32 + lane;
#pragma unroll 4
    for (int p = r0; p < r1; ++p) {
        int4 r = rec[p];                         // 16B wave-uniform load
        float ex = (lane < 32) ? __int_as_float(r.y) : __int_as_float(r.z);
        unsigned int pr = xlp[(size_t)r.x * 64]; // coalesced 256B/wave gather
        ss += ex;
        acc0 += ex * bf2f((unsigned short)(pr & 0xFFFFu));
        acc1 += ex * bf2f((unsigned short)(pr >> 16));
    }
    float inv = 1.f / (ss + 1e-16f);
    acc0 *= inv; acc1 *= inv;
    float o0 = 0.5f * (acc0 + __shfl_xor(acc0, 32));
    float o1 = 0.5f * (acc1 + __shfl_xor(acc1, 32));
    if (lane < 32) {
        float2 hv = ((const float2*)(hprev + (size_t)n * 64))[lane];
        if (use_bn) {
            float2 sc = ((const float2*)scsh)[lane];
            float2 sf = ((const float2*)(scsh + 64))[lane];
            hv.x = fmaxf(hv.x * sc.x + sf.x, 0.f);
            hv.y = fmaxf(hv.y * sc.y + sf.y, 0.f);
        }
        float2 bv = ((const float2*)bias)[lane];
        float2 o;
        o.x = o0 + bv.x + hv.x;
        o.y = o1 + bv.y + hv.y;
        ((float2*)(hnew + (size_t)n * 64))[lane] = o;
    }
}

// ---------- BN stats on pre-BN hbuf ----------
__global__ __launch_bounds__(256) void k_bnstat(const float* __restrict__ hbuf,
                                                float* __restrict__ part, float* __restrict__ partsq) {
    __shared__ float sA[256], sB[256];
    int t = threadIdx.x;
    int c = t & 63, r = t >> 6;
    int n0 = blockIdx.x * 80;
    float s = 0.f, s2 = 0.f;
    for (int i = 0; i < 20; ++i) {
        float v = hbuf[(size_t)(n0 + i * 4 + r) * 64 + c];
        s += v; s2 += v * v;
    }
    sA[t] = s; sB[t] = s2;
    __syncthreads();
    if (t < 64) {
        part[blockIdx.x * 64 + t]   = sA[t] + sA[t + 64] + sA[t + 128] + sA[t + 192];
        partsq[blockIdx.x * 64 + t] = sB[t] + sB[t + 64] + sB[t + 128] + sB[t + 192];
    }
}

__global__ __launch_bounds__(256) void k_bnred(const float* __restrict__ part, const float* __restrict__ partsq,
                                               const float* __restrict__ gamma, const float* __restrict__ beta,
                                               float* __restrict__ scsh) {
    __shared__ float sA[256], sB[256];
    int t = threadIdx.x;
    int c = t & 63, q = t >> 6;
    float s = 0.f, s2 = 0.f;
    for (int j = q; j < 250; j += 4) { s += part[j * 64 + c]; s2 += partsq[j * 64 + c]; }
    sA[t] = s; sB[t] = s2;
    __syncthreads();
    if (t < 64) {
        float su = sA[t] + sA[t + 64] + sA[t + 128] + sA[t + 192];
        float sq = sB[t] + sB[t + 64] + sB[t + 128] + sB[t + 192];
        float mu = su * (1.f / NN);
        float var = sq * (1.f / NN) - mu * mu;
        float sc = gamma[t] * rsqrtf(var + BN_EPS);
        scsh[t] = sc;
        scsh[64 + t] = beta[t] - mu * sc;
    }
}

extern "C" void kernel_launch(void* const* d_in, const int* in_sizes, int n_in,
                              void* d_out, int out_size, void* d_ws, size_t ws_size,
                              hipStream_t stream) {
    (void)in_sizes; (void)n_in; (void)out_size; (void)ws_size;
    const float* x     = (const float*)d_in[0];
    const int*   eidx  = (const int*)d_in[1];
    const float* eattr = (const float*)d_in[2];
    const float* instr = (const float*)d_in[3];
    const int*   batch = (const int*)d_in[4];
    const float* W_l   = (const float*)d_in[5];
    const float* W_e   = (const float*)d_in[6];
    const float* att_l = (const float*)d_in[7];
    const float* att_r = (const float*)d_in[8];
    const float* att_e = (const float*)d_in[9];
    const float* bias  = (const float*)d_in[10];
    const float* bn_g  = (const float*)d_in[11];
    const float* bn_b  = (const float*)d_in[12];
    float* out = (float*)d_out;

    const int* src = eidx;
    const int* dst = eidx + NE;

    char* ws = (char*)d_ws;
    float4* ae4     = (float4*)ws;     ws += (size_t)NE * 16;
    int4*   rec     = (int4*)ws;       ws += (size_t)NE * 16;
    unsigned short* xlh = (unsigned short*)ws; ws += (size_t)NN * 128 * 2;
    int*    csr_s   = (int*)ws;        ws += (size_t)NE * 4;
    int*    csr_d   = (int*)ws;        ws += (size_t)NE * 4;
    int*    deg     = (int*)ws;        ws += NN * 4;
    int*    rowptr  = (int*)ws;        ws += (NN + 1) * 4 + 4;
    int*    cursor  = (int*)ws;        ws += NN * 4;
    int*    bsum    = (int*)ws;        ws += 80 * 4;
    int*    boff    = (int*)ws;        ws += 80 * 4;
    float*  alc     = (float*)ws;      ws += NN * 2 * 4;
    float*  ar      = (float*)ws;      ws += NN * 2 * 4;
    float*  insl01  = (float*)ws;      ws += 2 * 128 * 128 * 4;
    float*  ve01    = (float*)ws;      ws += 256 * 4;
    float*  w2e01   = (float*)ws;      ws += 256 * 4;
    float*  ce01    = (float*)ws;      ws += 2 * 256 * 4;
    float*  hbuf    = (float*)ws;      ws += (size_t)NN * 64 * 4;
    float*  part    = (float*)ws;      ws += 250 * 64 * 4;
    float*  partsq  = (float*)ws;      ws += 250 * 64 * 4;
    float*  scsh    = (float*)ws;      ws += 128 * 4;

    hipMemsetAsync(deg, 0, NN * 4, stream);
    k_hist<<<(NE + 255) / 256, 256, 0, stream>>>(dst, deg);
    k_scanA<<<NBLK, 256, 0, stream>>>(deg, bsum);
    k_scanB<<<1, 64, 0, stream>>>(bsum, boff, rowptr);
    k_scanC<<<NBLK, 256, 0, stream>>>(deg, boff, rowptr, cursor);

    k_p1<<<2, 256, 0, stream>>>(W_e, att_e, ve01, w2e01);
    k_sced<<<(NE + 255) / 256, 256, 0, stream>>>(src, dst, eattr, ve01, cursor, csr_s, csr_d, ae4);
    k_p2both<<<130, 256, 0, stream>>>(instr, W_l, w2e01, insl01, ce01);

    for (int i = 0; i < 2; ++i) {
        const float* hcur = (i == 0) ? x : hbuf;
        float* hnew = (i == 0) ? hbuf : out;
        const float* Wl_i = W_l + (size_t)i * 128 * 128;

        k_node<<<(NN + 7) / 8, 256, 0, stream>>>(hcur, Wl_i, insl01 + (size_t)i * 16384, batch,
                                                 att_l + i * 128, att_r + i * 128,
                                                 (const float2*)(ce01 + i * 256),
                                                 scsh, i, xlh, alc, ar);
        k_attnexp<<<(NE + 255) / 256, 256, 0, stream>>>(csr_s, csr_d, ae4, i,
                                                        (const float2*)alc, (const float2*)ar, rec);
        k_gather<<<NN / 4, 256, 0, stream>>>(rowptr, rec, (const unsigned int*)xlh,
                                             bias + i * 64, hcur, scsh, i, hnew);
        if (i == 0) {
            k_bnstat<<<250, 256, 0, stream>>>(hbuf, part, partsq);
            k_bnred<<<1, 256, 0, stream>>>(part, partsq, bn_g, bn_b, scsh);
        }
    }
}